// Round 4
// baseline (397.655 us; speedup 1.0000x reference)
//
#include <hip/hip_runtime.h>
#include <hip/hip_bf16.h>
#include <stdint.h>

// XL multihead attention, L=S=2048, N=4, E=512, H=8, D=64.
// KEY INSIGHT: the reference's _rel_shift takes flat[:L*N*H] of a (L,S+1,N,H)
// tensor -> every element comes from l=0, so shifted term_bd[l,n,h,s] =
// term_bd[0,n,h,l] is CONSTANT over s => softmax-invariant => term_bd,
// rel_v, sin_pos_enc, rel_proj_w drop out of both outputs entirely.
// Remaining: standard MHA with rel_u query bias + head-mean att weights.
// R4: I/O dtype is ambiguous (reference declares fp32; harness may or may not
// downcast to bf16). A 1-wave detector classifies the actual storage dtype at
// runtime; all external loads/stores branch (wave-uniformly) on the flag.
// Internal pipeline stays bf16 MFMA.

#define L_Q 2048
#define S_K 2048
#define N_B 4
#define E_D 512
#define H_N 8
#define D_H 64

typedef unsigned short u16;
typedef short v8s __attribute__((ext_vector_type(8)));
typedef float v4f __attribute__((ext_vector_type(4)));

#define MFMA16(a, b, c) __builtin_amdgcn_mfma_f32_16x16x32_bf16(a, b, c, 0, 0, 0)

__device__ __forceinline__ float bf2f(u16 u) {
  unsigned int x = ((unsigned int)u) << 16;
  return __builtin_bit_cast(float, x);
}
__device__ __forceinline__ u16 f2bf(float f) {  // RNE
  unsigned int x = __builtin_bit_cast(unsigned int, f);
  x += 0x7FFFu + ((x >> 16) & 1u);
  return (u16)(x >> 16);
}
__device__ __forceinline__ float expc(float x) {  // clamped exp (finite always)
  return __expf(fminf(fmaxf(x, -30.f), 30.f));
}

// Load 8 consecutive elements as bf16x8 from either fp32 or bf16 storage.
__device__ __forceinline__ v8s ld8(const void* base, size_t e, int f32f) {
  if (f32f) {
    const float* p = (const float*)base + e;
    const v4f x0 = *(const v4f*)p;
    const v4f x1 = *(const v4f*)(p + 4);
    v8s r;
    r[0] = (short)f2bf(x0[0]); r[1] = (short)f2bf(x0[1]);
    r[2] = (short)f2bf(x0[2]); r[3] = (short)f2bf(x0[3]);
    r[4] = (short)f2bf(x1[0]); r[5] = (short)f2bf(x1[1]);
    r[6] = (short)f2bf(x1[2]); r[7] = (short)f2bf(x1[3]);
    return r;
  }
  return *(const v8s*)((const u16*)base + e);
}
__device__ __forceinline__ float ldel(const void* p, size_t i, int f32f) {
  return f32f ? ((const float*)p)[i] : bf2f(((const u16*)p)[i]);
}
__device__ __forceinline__ void stel(void* p, size_t i, float v, int f32f) {
  if (f32f) ((float*)p)[i] = v;
  else ((u16*)p)[i] = f2bf(v);
}

// Dtype detector: for bf16-packed storage, bits[14:7] of each u32 word are the
// low-half bf16's exponent -> clustered in [0x70,0x86] for N(0,1) data
// (~64/64 hits). For fp32 storage those bits are low mantissa -> uniform
// (~6/64 hits). Threshold 32.
__global__ void detect_k(const unsigned int* __restrict__ q,
                         int* __restrict__ flag) {
  const unsigned int w = q[threadIdx.x];
  const int e2 = (w >> 7) & 0xFF;
  const unsigned long long m = __ballot(e2 >= 0x70 && e2 <= 0x86);
  if (threadIdx.x == 0) *flag = (__popcll(m) < 32) ? 1 : 0;  // 1 = fp32
}

// ---------------- NT GEMM core: C(128x128) = A(Mx512) * W(512x512 rows)^T ----
// LDS: 4 k-octet planes, plane stride 1032 shorts. Wave w stages plane w:
// lane i's 16B at plane_base + i*16B. Frag reads are ds_read_b128.
__device__ __forceinline__ void gemm_core(const void* A, size_t abase,
                                          const void* W, size_t wbase, int af,
                                          int bf, int m0, int n0, u16* As,
                                          u16* Bs, v4f acc[4][4]) {
  const int lane = threadIdx.x & 63;
  const int w = threadIdx.x >> 6;
  const int wr = w >> 1, wc = w & 1;
  const int q = lane >> 4, c = lane & 15;
#pragma unroll
  for (int i = 0; i < 4; i++)
#pragma unroll
    for (int j = 0; j < 4; j++) acc[i][j] = (v4f){0.f, 0.f, 0.f, 0.f};
  for (int kk = 0; kk < 16; ++kk) {
    const size_t ea = abase + (size_t)(m0 + lane) * E_D + kk * 32 + w * 8;
    const size_t eb = wbase + (size_t)(n0 + lane) * E_D + kk * 32 + w * 8;
    const v8s va0 = ld8(A, ea, af);
    const v8s va1 = ld8(A, ea + (size_t)64 * E_D, af);
    const v8s vb0 = ld8(W, eb, bf);
    const v8s vb1 = ld8(W, eb + (size_t)64 * E_D, bf);
    __syncthreads();  // prior iteration's reads done before overwrite
    *(v8s*)(As + w * 1032 + lane * 8) = va0;
    *(v8s*)(As + w * 1032 + 512 + lane * 8) = va1;
    *(v8s*)(Bs + w * 1032 + lane * 8) = vb0;
    *(v8s*)(Bs + w * 1032 + 512 + lane * 8) = vb1;
    __syncthreads();
    v8s a[4], b[4];
#pragma unroll
    for (int i = 0; i < 4; i++)
      a[i] = *(const v8s*)(As + q * 1032 + (wr * 64 + i * 16 + c) * 8);
#pragma unroll
    for (int j = 0; j < 4; j++)
      b[j] = *(const v8s*)(Bs + q * 1032 + (wc * 64 + j * 16 + c) * 8);
#pragma unroll
    for (int i = 0; i < 4; i++)
#pragma unroll
      for (int j = 0; j < 4; j++) acc[i][j] = MFMA16(a[i], b[j], acc[i][j]);
  }
}

// qkv projections. z=0: Qw[n][h][l][d] = q + bias + rel_u (bf16)
//                 z=1: Kw[n][h][s][d]  z=2: Vt[n][h][d][s] (transposed for PV)
__global__ __launch_bounds__(256) void gemm_qkv(
    const void* __restrict__ query, const void* __restrict__ key_in,
    const void* __restrict__ value, const void* __restrict__ Wall,
    const void* __restrict__ bias, const void* __restrict__ rel_u,
    const int* __restrict__ flagp, u16* __restrict__ Qw, u16* __restrict__ Kw,
    u16* __restrict__ Vt) {
  __shared__ __align__(16) u16 As[4 * 1032];
  __shared__ __align__(16) u16 Bs[4 * 1032];
  const int f32f = *flagp;
  const int z = blockIdx.z;
  const void* A = (z == 0) ? query : ((z == 1) ? key_in : value);
  const int m0 = blockIdx.x * 128, n0 = blockIdx.y * 128;
  v4f acc[4][4];
  gemm_core(A, 0, Wall, (size_t)z * E_D * E_D, f32f, f32f, m0, n0, As, Bs, acc);
  const int lane = threadIdx.x & 63, w = threadIdx.x >> 6;
  const int wr = w >> 1, wc = w & 1;
  const int q = lane >> 4, c = lane & 15;
#pragma unroll
  for (int j = 0; j < 4; j++) {
    const int jg = n0 + wc * 64 + j * 16 + c;  // output feature = h*64+d
    const int h = jg >> 6, d = jg & 63;
    float add = ldel(bias, z * E_D + jg, f32f) +
                ((z == 0) ? ldel(rel_u, jg, f32f) : 0.f);
#pragma unroll
    for (int i = 0; i < 4; i++) {
#pragma unroll
      for (int r = 0; r < 4; r++) {
        const int mg = m0 + wr * 64 + i * 16 + q * 4 + r;  // row = l*4+n
        const int row = mg >> 2, nn = mg & 3;
        const u16 o = f2bf(acc[i][j][r] + add);
        if (z == 0)
          Qw[((size_t)(nn * H_N + h) * L_Q + row) * D_H + d] = o;
        else if (z == 1)
          Kw[((size_t)(nn * H_N + h) * S_K + row) * D_H + d] = o;
        else
          Vt[((size_t)(nn * H_N + h) * D_H + d) * S_K + row] = o;
      }
    }
  }
}

// out = Actx(8192x512) @ out_w^T + out_b -> d_out elements [0 : L*N*E)
__global__ __launch_bounds__(256) void gemm_out(const u16* __restrict__ Actx,
                                                const void* __restrict__ Wout,
                                                const void* __restrict__ bout,
                                                const int* __restrict__ flagp,
                                                void* __restrict__ out) {
  __shared__ __align__(16) u16 As[4 * 1032];
  __shared__ __align__(16) u16 Bs[4 * 1032];
  const int f32f = *flagp;
  const int m0 = blockIdx.x * 128, n0 = blockIdx.y * 128;
  v4f acc[4][4];
  gemm_core(Actx, 0, Wout, 0, 0, f32f, m0, n0, As, Bs, acc);
  const int lane = threadIdx.x & 63, w = threadIdx.x >> 6;
  const int wr = w >> 1, wc = w & 1;
  const int q = lane >> 4, c = lane & 15;
#pragma unroll
  for (int j = 0; j < 4; j++) {
    const int jg = n0 + wc * 64 + j * 16 + c;
    const float bb = ldel(bout, jg, f32f);
#pragma unroll
    for (int i = 0; i < 4; i++) {
#pragma unroll
      for (int r = 0; r < 4; r++) {
        const int mg = m0 + wr * 64 + i * 16 + q * 4 + r;
        stel(out, (size_t)mg * E_D + jg, acc[i][j][r] + bb, f32f);
      }
    }
  }
}

// Flash pass: per (n,h,l-tile of 64): sweep S in 64-chunks, P = exp(score/8),
// ctx += P@V via MFMA (P round-trips LDS C-layout->A-layout behind a barrier).
// All I/O is internal bf16. Writes Actx[l*4+n][h*64+d], Rbuf[nh][l]=1/rowsum.
__global__ __launch_bounds__(256) void flash_pv(
    const u16* __restrict__ Qw, const u16* __restrict__ Kw,
    const u16* __restrict__ Vt, u16* __restrict__ Actx,
    float* __restrict__ Rbuf) {
  __shared__ __align__(16) u16 Qs[8 * 520];  // 8 d-octet planes, stride 520
  __shared__ __align__(16) u16 Ks[8 * 520];
  __shared__ __align__(16) u16 Vs[8 * 520];            // planes = s-octets
  __shared__ __align__(16) short Ps[4 * 8 * 16 * 24];  // per-wave P
  const int lane = threadIdx.x & 63, w = threadIdx.x >> 6;
  const int q = lane >> 4, c = lane & 15;
  const int l0 = blockIdx.x * 64;
  const int nh = blockIdx.z * H_N + blockIdx.y;
  {
    const u16* g = Qw + ((size_t)nh * L_Q + l0 + lane) * D_H + w * 8;
    const v8s vq0 = *(const v8s*)g;
    const v8s vq1 = *(const v8s*)(g + 32);
    *(v8s*)(Qs + w * 520 + lane * 8) = vq0;
    *(v8s*)(Qs + (w + 4) * 520 + lane * 8) = vq1;
  }
  v4f ctx[4];
  float s_run[4];
#pragma unroll
  for (int i = 0; i < 4; i++) {
    ctx[i] = (v4f){0.f, 0.f, 0.f, 0.f};
    s_run[i] = 0.f;
  }
  __syncthreads();  // Q staged
  const v8s aq0 = *(const v8s*)(Qs + q * 520 + (w * 16 + c) * 8);
  const v8s aq1 = *(const v8s*)(Qs + (q + 4) * 520 + (w * 16 + c) * 8);
  short* pw = Ps + w * (8 * 16 * 24);
  for (int s0 = 0; s0 < S_K; s0 += 64) {
    const u16* gk = Kw + ((size_t)nh * S_K + s0 + lane) * D_H + w * 8;
    const u16* gv = Vt + ((size_t)nh * D_H + lane) * S_K + s0 + w * 8;
    const v8s vk0 = *(const v8s*)gk;
    const v8s vk1 = *(const v8s*)(gk + 32);
    const v8s vv0 = *(const v8s*)gv;
    const v8s vv1 = *(const v8s*)(gv + 32);
    __syncthreads();  // prior chunk's K/V reads done
    *(v8s*)(Ks + w * 520 + lane * 8) = vk0;
    *(v8s*)(Ks + (w + 4) * 520 + lane * 8) = vk1;
    *(v8s*)(Vs + w * 520 + lane * 8) = vv0;
    *(v8s*)(Vs + (w + 4) * 520 + lane * 8) = vv1;
    __syncthreads();
    v4f sv[4];
#pragma unroll
    for (int jt = 0; jt < 4; jt++) {
      const v8s bk0 = *(const v8s*)(Ks + q * 520 + (jt * 16 + c) * 8);
      const v8s bk1 = *(const v8s*)(Ks + (q + 4) * 520 + (jt * 16 + c) * 8);
      v4f zz = (v4f){0.f, 0.f, 0.f, 0.f};
      zz = MFMA16(aq0, bk0, zz);
      zz = MFMA16(aq1, bk1, zz);
      sv[jt] = zz;
    }
    // P = exp(score/8); store bf16 into per-wave Ps (C-layout -> A-layout)
#pragma unroll
    for (int r = 0; r < 4; r++) {
      const int row = q * 4 + r;
#pragma unroll
      for (int jt = 0; jt < 4; jt++) {
        const float p = expc(sv[jt][r] * 0.125f);
        s_run[r] += p;
        const int sl = jt * 16 + c;
        pw[((sl >> 3) * 16 + row) * 24 + (sl & 7)] = (short)f2bf(p);
      }
    }
    __syncthreads();  // order P store -> P read
    const v8s ap0 = *(const v8s*)(pw + (q * 16 + c) * 24);
    const v8s ap1 = *(const v8s*)(pw + ((q + 4) * 16 + c) * 24);
#pragma unroll
    for (int ds = 0; ds < 4; ds++) {
      const v8s bv0 = *(const v8s*)(Vs + q * 520 + (ds * 16 + c) * 8);
      const v8s bv1 = *(const v8s*)(Vs + (q + 4) * 520 + (ds * 16 + c) * 8);
      ctx[ds] = MFMA16(ap0, bv0, ctx[ds]);
      ctx[ds] = MFMA16(ap1, bv1, ctx[ds]);
    }
  }
  // reduce row sums across the 16 lanes of each quad (4 cols/lane/chunk)
#pragma unroll
  for (int r = 0; r < 4; r++) {
    float s = s_run[r];
    s += __shfl_xor(s, 1);
    s += __shfl_xor(s, 2);
    s += __shfl_xor(s, 4);
    s += __shfl_xor(s, 8);
    s_run[r] = s;
  }
#pragma unroll
  for (int r = 0; r < 4; r++) {
    const float rr = 1.0f / s_run[r];
    const int l = l0 + w * 16 + q * 4 + r;
#pragma unroll
    for (int ds = 0; ds < 4; ds++) {
      Actx[((size_t)l * N_B + blockIdx.z) * E_D + blockIdx.y * D_H + ds * 16 +
           c] = f2bf(ctx[ds][r] * rr);
    }
    if (c == 0) Rbuf[(size_t)nh * L_Q + l] = rr;
  }
}

// attw pass: per (n, l-tile 64, s-chunk 256): loop all 8 heads in-block,
// recompute scores, P = exp(s/8)*r, write mean/8 to d_out elements
// [L*N*E + n*L*S + l*S + s].
__global__ __launch_bounds__(256) void attw_k(const u16* __restrict__ Qw,
                                              const u16* __restrict__ Kw,
                                              const float* __restrict__ Rbuf,
                                              const int* __restrict__ flagp,
                                              void* __restrict__ outb) {
  __shared__ __align__(16) u16 Qs[8 * 520];
  __shared__ __align__(16) u16 Ks[8 * 520];
  const int f32f = *flagp;
  const int lane = threadIdx.x & 63, w = threadIdx.x >> 6;
  const int q = lane >> 4, c = lane & 15;
  const int s_base = blockIdx.x * 256;
  const int l0 = blockIdx.y * 64;
  const int n = blockIdx.z;
  const size_t out0 = (size_t)L_Q * N_B * E_D;
  v4f aw[4][4];
#pragma unroll
  for (int ss = 0; ss < 4; ss++)
#pragma unroll
    for (int jt = 0; jt < 4; jt++) aw[ss][jt] = (v4f){0.f, 0.f, 0.f, 0.f};
  for (int h = 0; h < H_N; ++h) {
    const int nh = n * H_N + h;
    float rr[4];
#pragma unroll
    for (int r = 0; r < 4; r++)
      rr[r] = Rbuf[(size_t)nh * L_Q + l0 + w * 16 + q * 4 + r];
    v8s aq0, aq1;
    for (int ss = 0; ss < 4; ++ss) {
      const u16* gk =
          Kw + ((size_t)nh * S_K + s_base + ss * 64 + lane) * D_H + w * 8;
      const v8s vk0 = *(const v8s*)gk;
      const v8s vk1 = *(const v8s*)(gk + 32);
      v8s vq0, vq1;
      if (ss == 0) {
        const u16* g = Qw + ((size_t)nh * L_Q + l0 + lane) * D_H + w * 8;
        vq0 = *(const v8s*)g;
        vq1 = *(const v8s*)(g + 32);
      }
      __syncthreads();  // prior reads of Qs/Ks done
      if (ss == 0) {
        *(v8s*)(Qs + w * 520 + lane * 8) = vq0;
        *(v8s*)(Qs + (w + 4) * 520 + lane * 8) = vq1;
      }
      *(v8s*)(Ks + w * 520 + lane * 8) = vk0;
      *(v8s*)(Ks + (w + 4) * 520 + lane * 8) = vk1;
      __syncthreads();
      if (ss == 0) {
        aq0 = *(const v8s*)(Qs + q * 520 + (w * 16 + c) * 8);
        aq1 = *(const v8s*)(Qs + (q + 4) * 520 + (w * 16 + c) * 8);
      }
#pragma unroll
      for (int jt = 0; jt < 4; jt++) {
        const v8s bk0 = *(const v8s*)(Ks + q * 520 + (jt * 16 + c) * 8);
        const v8s bk1 = *(const v8s*)(Ks + (q + 4) * 520 + (jt * 16 + c) * 8);
        v4f zz = (v4f){0.f, 0.f, 0.f, 0.f};
        zz = MFMA16(aq0, bk0, zz);
        zz = MFMA16(aq1, bk1, zz);
#pragma unroll
        for (int r = 0; r < 4; r++)
          aw[ss][jt][r] += expc(zz[r] * 0.125f) * rr[r];
      }
    }
  }
#pragma unroll
  for (int ss = 0; ss < 4; ss++)
#pragma unroll
    for (int jt = 0; jt < 4; jt++)
#pragma unroll
      for (int r = 0; r < 4; r++) {
        const int l = l0 + w * 16 + q * 4 + r;
        const int s = s_base + ss * 64 + jt * 16 + c;
        stel(outb, out0 + ((size_t)n * L_Q + l) * S_K + s,
             aw[ss][jt][r] * 0.125f, f32f);
      }
}

extern "C" void kernel_launch(void* const* d_in, const int* in_sizes, int n_in,
                              void* d_out, int out_size, void* d_ws,
                              size_t ws_size, hipStream_t stream) {
  const void* query = d_in[0];
  const void* key_in = d_in[1];
  const void* value = d_in[2];
  // d_in[3] sin_pos_enc, d_in[8] rel_proj_w, d_in[10] rel_v: drop out (see top)
  const void* Wall = d_in[4];
  const void* bias = d_in[5];
  const void* Wout = d_in[6];
  const void* bout = d_in[7];
  const void* rel_u = d_in[9];

  char* ws = (char*)d_ws;
  u16* Qw = (u16*)(ws);                   // 8 MB  (N,H,L,D) bf16
  u16* Kw = (u16*)(ws + 8388608);         // 8 MB  (N,H,S,D)
  u16* Vt = (u16*)(ws + 16777216);        // 8 MB  (N,H,D,S)
  u16* Actx = (u16*)(ws + 25165824);      // 8 MB  (L*N, E)
  float* Rbuf = (float*)(ws + 33554432);  // 256 KB (N*H, L)
  int* flagp = (int*)(ws + 33816576);     // 4 B dtype flag (1 = fp32 I/O)

  hipLaunchKernelGGL(detect_k, dim3(1), dim3(64), 0, stream,
                     (const unsigned int*)query, flagp);
  hipLaunchKernelGGL(gemm_qkv, dim3(64, 4, 3), dim3(256), 0, stream, query,
                     key_in, value, Wall, bias, rel_u, flagp, Qw, Kw, Vt);
  hipLaunchKernelGGL(flash_pv, dim3(32, 8, 4), dim3(256), 0, stream, Qw, Kw, Vt,
                     Actx, Rbuf);
  hipLaunchKernelGGL(attw_k, dim3(8, 32, 4), dim3(256), 0, stream, Qw, Kw, Rbuf,
                     flagp, d_out);
  hipLaunchKernelGGL(gemm_out, dim3(64, 4, 1), dim3(256), 0, stream, Actx, Wout,
                     bout, flagp, d_out);
}

// Round 5
// 340.483 us; speedup vs baseline: 1.1679x; 1.1679x over previous
//
#include <hip/hip_runtime.h>
#include <hip/hip_bf16.h>
#include <stdint.h>

// XL multihead attention, L=S=2048, N=4, E=512, H=8, D=64.  I/O = fp32
// (confirmed R4: PASS absmax 4.9e-4 with runtime dtype detector -> fp32).
// _rel_shift collapses to a per-row constant (softmax-invariant) => term_bd,
// rel_v, sin_pos_enc, rel_proj_w drop out. Remaining: MHA with rel_u q-bias
// + head-mean att weights.
// R5: pre-convert fp32->bf16 once; pure-bf16 GEMM staging; flash_pv LDS
// 49.7->33.2KB (4 blocks/CU) + P-roundtrip barrier -> threadfence.

#define L_Q 2048
#define S_K 2048
#define N_B 4
#define E_D 512
#define H_N 8
#define D_H 64

typedef unsigned short u16;
typedef short v8s __attribute__((ext_vector_type(8)));
typedef float v4f __attribute__((ext_vector_type(4)));

#define MFMA16(a, b, c) __builtin_amdgcn_mfma_f32_16x16x32_bf16(a, b, c, 0, 0, 0)

__device__ __forceinline__ float bf2f(u16 u) {
  unsigned int x = ((unsigned int)u) << 16;
  return __builtin_bit_cast(float, x);
}
__device__ __forceinline__ u16 f2bf(float f) {  // RNE
  unsigned int x = __builtin_bit_cast(unsigned int, f);
  x += 0x7FFFu + ((x >> 16) & 1u);
  return (u16)(x >> 16);
}
__device__ __forceinline__ float expc(float x) {  // clamped exp (finite always)
  return __expf(fminf(fmaxf(x, -30.f), 30.f));
}

// ---- bulk fp32 -> bf16 converter over 8 segments ----
struct Cvt8 {
  const float* s[8];
  u16* d[8];
};
__global__ __launch_bounds__(256) void cvt_k(Cvt8 a) {
  const size_t t = ((size_t)blockIdx.x * 256 + threadIdx.x) * 4;
  // seg sizes: q 4194304, k 4194304, v 4194304, Wall 786432, Wout 262144,
  // bias 1536, bout 512, rel_u 512 (all multiples of 4)
  const size_t cum[9] = {0,        4194304,  8388608,  12582912, 13369344,
                         13631488, 13633024, 13633536, 13634048};
  if (t >= cum[8]) return;
  int sg = 0;
#pragma unroll
  for (int i = 1; i < 8; i++) sg += (t >= cum[i]);
  const size_t off = t - cum[sg];
  const v4f x = *(const v4f*)(a.s[sg] + off);
  ushort4 o;
  o.x = f2bf(x[0]);
  o.y = f2bf(x[1]);
  o.z = f2bf(x[2]);
  o.w = f2bf(x[3]);
  *(ushort4*)(a.d[sg] + off) = o;
}

// ---------------- NT GEMM core: C(128x128) = A(Mx512) * W(512 rows)^T ------
// LDS: 4 k-octet planes, plane stride 1032 shorts. Wave w stages plane w:
// lane i's 16B at plane_base + i*16B. Frag reads are ds_read_b128.
__device__ __forceinline__ void gemm_core(const u16* A, const u16* W, int m0,
                                          int n0, u16* As, u16* Bs,
                                          v4f acc[4][4]) {
  const int lane = threadIdx.x & 63;
  const int w = threadIdx.x >> 6;
  const int wr = w >> 1, wc = w & 1;
  const int q = lane >> 4, c = lane & 15;
#pragma unroll
  for (int i = 0; i < 4; i++)
#pragma unroll
    for (int j = 0; j < 4; j++) acc[i][j] = (v4f){0.f, 0.f, 0.f, 0.f};
  for (int kk = 0; kk < 16; ++kk) {
    const u16* ga = A + (size_t)(m0 + lane) * E_D + kk * 32 + w * 8;
    const u16* gb = W + (size_t)(n0 + lane) * E_D + kk * 32 + w * 8;
    const v8s va0 = *(const v8s*)ga;
    const v8s va1 = *(const v8s*)(ga + 64 * E_D);
    const v8s vb0 = *(const v8s*)gb;
    const v8s vb1 = *(const v8s*)(gb + 64 * E_D);
    __syncthreads();  // prior iteration's reads done before overwrite
    *(v8s*)(As + w * 1032 + lane * 8) = va0;
    *(v8s*)(As + w * 1032 + 512 + lane * 8) = va1;
    *(v8s*)(Bs + w * 1032 + lane * 8) = vb0;
    *(v8s*)(Bs + w * 1032 + 512 + lane * 8) = vb1;
    __syncthreads();
    v8s a[4], b[4];
#pragma unroll
    for (int i = 0; i < 4; i++)
      a[i] = *(const v8s*)(As + q * 1032 + (wr * 64 + i * 16 + c) * 8);
#pragma unroll
    for (int j = 0; j < 4; j++)
      b[j] = *(const v8s*)(Bs + q * 1032 + (wc * 64 + j * 16 + c) * 8);
#pragma unroll
    for (int i = 0; i < 4; i++)
#pragma unroll
      for (int j = 0; j < 4; j++) acc[i][j] = MFMA16(a[i], b[j], acc[i][j]);
  }
}

// qkv projections (all-bf16). z=0: Qw[n][h][l][d] = q + bias + rel_u
//   z=1: Kw[n][h][s][d]   z=2: Vt[n][h][d][s] (transposed for PV)
__global__ __launch_bounds__(256) void gemm_qkv(
    const u16* __restrict__ qb, const u16* __restrict__ kb,
    const u16* __restrict__ vb, const u16* __restrict__ Wallb,
    const u16* __restrict__ biasb, const u16* __restrict__ rel_ub,
    u16* __restrict__ Qw, u16* __restrict__ Kw, u16* __restrict__ Vt) {
  __shared__ __align__(16) u16 As[4 * 1032];
  __shared__ __align__(16) u16 Bs[4 * 1032];
  const int z = blockIdx.z;
  const u16* A = (z == 0) ? qb : ((z == 1) ? kb : vb);
  const int m0 = blockIdx.x * 128, n0 = blockIdx.y * 128;
  v4f acc[4][4];
  gemm_core(A, Wallb + (size_t)z * E_D * E_D, m0, n0, As, Bs, acc);
  const int lane = threadIdx.x & 63, w = threadIdx.x >> 6;
  const int wr = w >> 1, wc = w & 1;
  const int q = lane >> 4, c = lane & 15;
#pragma unroll
  for (int j = 0; j < 4; j++) {
    const int jg = n0 + wc * 64 + j * 16 + c;  // output feature = h*64+d
    const int h = jg >> 6, d = jg & 63;
    float add =
        bf2f(biasb[z * E_D + jg]) + ((z == 0) ? bf2f(rel_ub[jg]) : 0.f);
#pragma unroll
    for (int i = 0; i < 4; i++) {
#pragma unroll
      for (int r = 0; r < 4; r++) {
        const int mg = m0 + wr * 64 + i * 16 + q * 4 + r;  // row = l*4+n
        const int row = mg >> 2, nn = mg & 3;
        const u16 o = f2bf(acc[i][j][r] + add);
        if (z == 0)
          Qw[((size_t)(nn * H_N + h) * L_Q + row) * D_H + d] = o;
        else if (z == 1)
          Kw[((size_t)(nn * H_N + h) * S_K + row) * D_H + d] = o;
        else
          Vt[((size_t)(nn * H_N + h) * D_H + d) * S_K + row] = o;
      }
    }
  }
}

// out = Actx(8192x512)bf16 @ Woutb^T + bout -> fp32 d_out[0 : L*N*E)
__global__ __launch_bounds__(256) void gemm_out(const u16* __restrict__ Actx,
                                                const u16* __restrict__ Woutb,
                                                const u16* __restrict__ boutb,
                                                float* __restrict__ out) {
  __shared__ __align__(16) u16 As[4 * 1032];
  __shared__ __align__(16) u16 Bs[4 * 1032];
  const int m0 = blockIdx.x * 128, n0 = blockIdx.y * 128;
  v4f acc[4][4];
  gemm_core(Actx, Woutb, m0, n0, As, Bs, acc);
  const int lane = threadIdx.x & 63, w = threadIdx.x >> 6;
  const int wr = w >> 1, wc = w & 1;
  const int q = lane >> 4, c = lane & 15;
#pragma unroll
  for (int j = 0; j < 4; j++) {
    const int jg = n0 + wc * 64 + j * 16 + c;
    const float bb = bf2f(boutb[jg]);
#pragma unroll
    for (int i = 0; i < 4; i++) {
#pragma unroll
      for (int r = 0; r < 4; r++) {
        const int mg = m0 + wr * 64 + i * 16 + q * 4 + r;
        out[(size_t)mg * E_D + jg] = acc[i][j][r] + bb;
      }
    }
  }
}

// Flash pass: per (n,h,l-tile 64): sweep S in 64-chunks, P = exp(score/8),
// ctx += P@V via MFMA. P round-trips per-WAVE LDS (C-layout -> A-layout);
// since each wave reads only its own P region, a threadfence_block (not a
// barrier) orders store->read. LDS 33.2KB -> 4 blocks/CU.
__global__ __launch_bounds__(256) void flash_pv(
    const u16* __restrict__ Qw, const u16* __restrict__ Kw,
    const u16* __restrict__ Vt, u16* __restrict__ Actx,
    float* __restrict__ Rbuf) {
  __shared__ __align__(16) u16 Qs[8 * 520];  // 8 d-octet planes, stride 520
  __shared__ __align__(16) u16 Ks[8 * 520];
  __shared__ __align__(16) u16 Vs[8 * 520];        // planes = s-octets
  __shared__ __align__(16) short Ps[4 * 8 * 16 * 8];  // per-wave P, tight
  const int lane = threadIdx.x & 63, w = threadIdx.x >> 6;
  const int q = lane >> 4, c = lane & 15;
  const int l0 = blockIdx.x * 64;
  const int nh = blockIdx.z * H_N + blockIdx.y;
  {
    const u16* g = Qw + ((size_t)nh * L_Q + l0 + lane) * D_H + w * 8;
    const v8s vq0 = *(const v8s*)g;
    const v8s vq1 = *(const v8s*)(g + 32);
    *(v8s*)(Qs + w * 520 + lane * 8) = vq0;
    *(v8s*)(Qs + (w + 4) * 520 + lane * 8) = vq1;
  }
  v4f ctx[4];
  float s_run[4];
#pragma unroll
  for (int i = 0; i < 4; i++) {
    ctx[i] = (v4f){0.f, 0.f, 0.f, 0.f};
    s_run[i] = 0.f;
  }
  __syncthreads();  // Q staged
  const v8s aq0 = *(const v8s*)(Qs + q * 520 + (w * 16 + c) * 8);
  const v8s aq1 = *(const v8s*)(Qs + (q + 4) * 520 + (w * 16 + c) * 8);
  short* pw = Ps + w * (8 * 16 * 8);
  for (int s0 = 0; s0 < S_K; s0 += 64) {
    const u16* gk = Kw + ((size_t)nh * S_K + s0 + lane) * D_H + w * 8;
    const u16* gv = Vt + ((size_t)nh * D_H + lane) * S_K + s0 + w * 8;
    const v8s vk0 = *(const v8s*)gk;
    const v8s vk1 = *(const v8s*)(gk + 32);
    const v8s vv0 = *(const v8s*)gv;
    const v8s vv1 = *(const v8s*)(gv + 32);
    __syncthreads();  // prior chunk's K/V reads done
    *(v8s*)(Ks + w * 520 + lane * 8) = vk0;
    *(v8s*)(Ks + (w + 4) * 520 + lane * 8) = vk1;
    *(v8s*)(Vs + w * 520 + lane * 8) = vv0;
    *(v8s*)(Vs + (w + 4) * 520 + lane * 8) = vv1;
    __syncthreads();
    v4f sv[4];
#pragma unroll
    for (int jt = 0; jt < 4; jt++) {
      const v8s bk0 = *(const v8s*)(Ks + q * 520 + (jt * 16 + c) * 8);
      const v8s bk1 = *(const v8s*)(Ks + (q + 4) * 520 + (jt * 16 + c) * 8);
      v4f zz = (v4f){0.f, 0.f, 0.f, 0.f};
      zz = MFMA16(aq0, bk0, zz);
      zz = MFMA16(aq1, bk1, zz);
      sv[jt] = zz;
    }
    // P = exp(score/8); per-wave Ps layout [s-octet][row][8]
#pragma unroll
    for (int r = 0; r < 4; r++) {
      const int row = q * 4 + r;
#pragma unroll
      for (int jt = 0; jt < 4; jt++) {
        const float p = expc(sv[jt][r] * 0.125f);
        s_run[r] += p;
        const int sl = jt * 16 + c;
        pw[((sl >> 3) * 16 + row) * 8 + (sl & 7)] = (short)f2bf(p);
      }
    }
    __threadfence_block();  // wave-local P store->read ordering (own region)
    const v8s ap0 = *(const v8s*)(pw + (q * 16 + c) * 8);
    const v8s ap1 = *(const v8s*)(pw + ((q + 4) * 16 + c) * 8);
#pragma unroll
    for (int ds = 0; ds < 4; ds++) {
      const v8s bv0 = *(const v8s*)(Vs + q * 520 + (ds * 16 + c) * 8);
      const v8s bv1 = *(const v8s*)(Vs + (q + 4) * 520 + (ds * 16 + c) * 8);
      ctx[ds] = MFMA16(ap0, bv0, ctx[ds]);
      ctx[ds] = MFMA16(ap1, bv1, ctx[ds]);
    }
  }
  // reduce row sums across the 16 lanes of each quad (4 cols/lane/chunk)
#pragma unroll
  for (int r = 0; r < 4; r++) {
    float s = s_run[r];
    s += __shfl_xor(s, 1);
    s += __shfl_xor(s, 2);
    s += __shfl_xor(s, 4);
    s += __shfl_xor(s, 8);
    s_run[r] = s;
  }
#pragma unroll
  for (int r = 0; r < 4; r++) {
    const float rr = 1.0f / s_run[r];
    const int l = l0 + w * 16 + q * 4 + r;
#pragma unroll
    for (int ds = 0; ds < 4; ds++) {
      Actx[((size_t)l * N_B + blockIdx.z) * E_D + blockIdx.y * D_H + ds * 16 +
           c] = f2bf(ctx[ds][r] * rr);
    }
    if (c == 0) Rbuf[(size_t)nh * L_Q + l] = rr;
  }
}

// attw pass (runs LAST; overwrites the d_out scratch region with the real
// attention-weight output): per (n, l-tile 64, s-chunk 256): loop 8 heads
// in-block, recompute scores, accumulate exp(s/8)*r, write mean/8 as fp32.
__global__ __launch_bounds__(256) void attw_k(const u16* __restrict__ Qw,
                                              const u16* __restrict__ Kw,
                                              const float* __restrict__ Rbuf,
                                              float* __restrict__ AW) {
  __shared__ __align__(16) u16 Qs[8 * 520];
  __shared__ __align__(16) u16 Ks[8 * 520];
  const int lane = threadIdx.x & 63, w = threadIdx.x >> 6;
  const int q = lane >> 4, c = lane & 15;
  const int s_base = blockIdx.x * 256;
  const int l0 = blockIdx.y * 64;
  const int n = blockIdx.z;
  v4f aw[4][4];
#pragma unroll
  for (int ss = 0; ss < 4; ss++)
#pragma unroll
    for (int jt = 0; jt < 4; jt++) aw[ss][jt] = (v4f){0.f, 0.f, 0.f, 0.f};
  for (int h = 0; h < H_N; ++h) {
    const int nh = n * H_N + h;
    float rr[4];
#pragma unroll
    for (int r = 0; r < 4; r++)
      rr[r] = Rbuf[(size_t)nh * L_Q + l0 + w * 16 + q * 4 + r];
    v8s aq0, aq1;
    for (int ss = 0; ss < 4; ++ss) {
      const u16* gk =
          Kw + ((size_t)nh * S_K + s_base + ss * 64 + lane) * D_H + w * 8;
      const v8s vk0 = *(const v8s*)gk;
      const v8s vk1 = *(const v8s*)(gk + 32);
      v8s vq0, vq1;
      if (ss == 0) {
        const u16* g = Qw + ((size_t)nh * L_Q + l0 + lane) * D_H + w * 8;
        vq0 = *(const v8s*)g;
        vq1 = *(const v8s*)(g + 32);
      }
      __syncthreads();  // prior reads of Qs/Ks done
      if (ss == 0) {
        *(v8s*)(Qs + w * 520 + lane * 8) = vq0;
        *(v8s*)(Qs + (w + 4) * 520 + lane * 8) = vq1;
      }
      *(v8s*)(Ks + w * 520 + lane * 8) = vk0;
      *(v8s*)(Ks + (w + 4) * 520 + lane * 8) = vk1;
      __syncthreads();
      if (ss == 0) {
        aq0 = *(const v8s*)(Qs + q * 520 + (w * 16 + c) * 8);
        aq1 = *(const v8s*)(Qs + (q + 4) * 520 + (w * 16 + c) * 8);
      }
#pragma unroll
      for (int jt = 0; jt < 4; jt++) {
        const v8s bk0 = *(const v8s*)(Ks + q * 520 + (jt * 16 + c) * 8);
        const v8s bk1 = *(const v8s*)(Ks + (q + 4) * 520 + (jt * 16 + c) * 8);
        v4f zz = (v4f){0.f, 0.f, 0.f, 0.f};
        zz = MFMA16(aq0, bk0, zz);
        zz = MFMA16(aq1, bk1, zz);
#pragma unroll
        for (int r = 0; r < 4; r++)
          aw[ss][jt][r] += expc(zz[r] * 0.125f) * rr[r];
      }
    }
  }
#pragma unroll
  for (int ss = 0; ss < 4; ss++)
#pragma unroll
    for (int jt = 0; jt < 4; jt++)
#pragma unroll
      for (int r = 0; r < 4; r++) {
        const int l = l0 + w * 16 + q * 4 + r;
        const int s = s_base + ss * 64 + jt * 16 + c;
        AW[((size_t)n * L_Q + l) * S_K + s] = aw[ss][jt][r] * 0.125f;
      }
}

extern "C" void kernel_launch(void* const* d_in, const int* in_sizes, int n_in,
                              void* d_out, int out_size, void* d_ws,
                              size_t ws_size, hipStream_t stream) {
  // ws layout (<= 29.7 MB, proven safe at 33.8 in R4)
  char* ws = (char*)d_ws;
  u16* Wallb = (u16*)(ws);                 // 1.57 MB
  u16* Woutb = (u16*)(ws + 1572864);       // 0.52 MB
  u16* biasb = (u16*)(ws + 2097152);       // 3 KB
  u16* boutb = (u16*)(ws + 2100224);       // 1 KB
  u16* rel_ub = (u16*)(ws + 2101248);      // 1 KB
  u16* Qw = (u16*)(ws + 4194304);          // 8 MB (N,H,L,D)
  u16* Kw = (u16*)(ws + 12582912);         // 8 MB (N,H,S,D)
  u16* Vt = (u16*)(ws + 20971520);         // 8 MB (N,H,D,S)
  float* Rbuf = (float*)(ws + 29360128);   // 256 KB (N*H, L)

  // scratch inside d_out's attw region (67 MB; overwritten by attw_k LAST)
  float* out = (float*)d_out;
  char* sc = (char*)d_out + 16777216;
  u16* qb = (u16*)(sc);              // 8 MB converted query
  u16* kb = (u16*)(sc + 8388608);    // 8 MB converted key
  u16* vb = (u16*)(sc + 16777216);   // 8 MB converted value
  u16* Actx = (u16*)(sc + 25165824); // 8 MB context (L*4+n, E)
  float* AW = out + (size_t)L_Q * N_B * E_D;

  Cvt8 a;
  a.s[0] = (const float*)d_in[0];  a.d[0] = qb;      // query
  a.s[1] = (const float*)d_in[1];  a.d[1] = kb;      // key
  a.s[2] = (const float*)d_in[2];  a.d[2] = vb;      // value
  a.s[3] = (const float*)d_in[4];  a.d[3] = Wallb;   // in_proj_weight
  a.s[4] = (const float*)d_in[6];  a.d[4] = Woutb;   // out_w
  a.s[5] = (const float*)d_in[5];  a.d[5] = biasb;   // in_proj_bias
  a.s[6] = (const float*)d_in[7];  a.d[6] = boutb;   // out_b
  a.s[7] = (const float*)d_in[9];  a.d[7] = rel_ub;  // rel_u
  // d_in[3] sin_pos_enc, d_in[8] rel_proj_w, d_in[10] rel_v: algebraically out

  hipLaunchKernelGGL(cvt_k, dim3(13315), dim3(256), 0, stream, a);
  hipLaunchKernelGGL(gemm_qkv, dim3(64, 4, 3), dim3(256), 0, stream, qb, kb,
                     vb, Wallb, biasb, rel_ub, Qw, Kw, Vt);
  hipLaunchKernelGGL(flash_pv, dim3(32, 8, 4), dim3(256), 0, stream, Qw, Kw,
                     Vt, Actx, Rbuf);
  hipLaunchKernelGGL(gemm_out, dim3(64, 4, 1), dim3(256), 0, stream, Actx,
                     Woutb, boutb, out);
  hipLaunchKernelGGL(attw_k, dim3(8, 32, 4), dim3(256), 0, stream, Qw, Kw,
                     Rbuf, AW);
}